// Round 2
// baseline (1353.024 us; speedup 1.0000x reference)
//
#include <hip/hip_runtime.h>

// ---------------------------------------------------------------------------
// Cylindrical flow: h = relu(x@W1+b1); params = (h@W2+b2)*eta; circular RQ
// spline. B=1048576, N=64, H=256, nb=32.
// Precision strategy: split-bf16 (hi+lo) 3-term MFMA for both GEMMs
// (effective ~fp32 logits; bf16-only logit noise 0.0043 amplified ~70x by
// narrow spline bins caused R1's 0.297 absmax).
// Memory strategy: weights prepped to hi/lo bf16 in d_ws, read from global
// (L2-cached broadcast); X read from global fp32 + VALU split; only H goes
// through LDS (hi/lo, XOR-swizzled, 64 KiB -> 2 blocks/CU).
// ---------------------------------------------------------------------------

typedef __bf16 bf16x4 __attribute__((ext_vector_type(4)));
typedef __bf16 bf16x8 __attribute__((ext_vector_type(8)));
typedef float  f32x4  __attribute__((ext_vector_type(4)));

#define TWO_PI_F  6.28318530717958647692f
#define MIN_SZ    1e-3f
#define MIN_D_F   1e-3f
#define DERIV_OFF 0.54132485461291810f   /* ln(e-1) */

__device__ __forceinline__ float softplus_f(float x) {
    return fmaxf(x, 0.f) + log1pf(__expf(-fabsf(x)));
}

// Swizzled LDS offset (elements) for H: (row r, col h), row stride 256,
// 8-elem chunks XORed by r&7 -> conflict-free b128 reads at any k0%8==0.
__device__ __forceinline__ int hswz(int r, int h) {
    return r * 256 + ((((h >> 3) ^ (r & 7)) << 3) | (h & 7));
}

__global__ void flow_prep(const float* __restrict__ W1, const float* __restrict__ W2,
                          __bf16* __restrict__ w1hi, __bf16* __restrict__ w1lo,
                          __bf16* __restrict__ w2hi, __bf16* __restrict__ w2lo) {
    int i = blockIdx.x * 256 + threadIdx.x;
    if (i < 64 * 256) {                    // w1t[h][n] from W1 (64,256)
        int h = i >> 6, n = i & 63;
        float v = W1[n * 256 + h];
        __bf16 hb = (__bf16)v;
        w1hi[i] = hb;
        w1lo[i] = (__bf16)(v - (float)hb);
    }
    int j = i - 64 * 256;
    if (j >= 0 && j < 96 * 256) {          // w2t[p][k] from W2 (256,96)
        int p = j >> 8, k = j & 255;
        float v = W2[k * 96 + p];
        __bf16 hb = (__bf16)v;
        w2hi[j] = hb;
        w2lo[j] = (__bf16)(v - (float)hb);
    }
}

__global__ __launch_bounds__(512, 4) void flow_main(
    const float* __restrict__ theta, const float* __restrict__ xc,
    const float* __restrict__ b1g, const float* __restrict__ b2g,
    const float* __restrict__ etag,
    const __bf16* __restrict__ w1hi, const __bf16* __restrict__ w1lo,
    const __bf16* __restrict__ w2hi, const __bf16* __restrict__ w2lo,
    float* __restrict__ out, int Btot)
{
    __shared__ __align__(16) char smem[65536];
    __bf16* sHhi = (__bf16*)smem;             // [64][256] swizzled, 32 KiB
    __bf16* sHlo = (__bf16*)(smem + 32768);   // [64][256] swizzled, 32 KiB
    float*  sP   = (float*)smem;              // [64][97], aliases sHhi (post-barrier)

    const int t    = threadIdx.x;
    const int w    = t >> 6;
    const int l    = t & 63;
    const int quad = l >> 4;
    const int lc   = l & 15;
    const long R0  = (long)blockIdx.x * 64;

    // ---- Phase A: GEMM1  H^T(256x64) = W1T(256x64-k) @ X^T(64x64) ----------
    // wave: hg = w>>1 -> h-tiles hg*4+i; ng = w&1 -> batch-tiles ng*2+j
    {
        const int hg = w >> 1, ng = w & 1;
        f32x4 acc[4][2] = {};
        #pragma unroll
        for (int kb = 0; kb < 2; ++kb) {
            const int k0 = kb * 32 + quad * 8;
            bf16x8 ahi[4], alo[4], bhi[2], blo[2];
            #pragma unroll
            for (int i = 0; i < 4; ++i) {
                int hr = (hg * 4 + i) * 16 + lc;
                ahi[i] = *(const bf16x8*)(w1hi + hr * 64 + k0);
                alo[i] = *(const bf16x8*)(w1lo + hr * 64 + k0);
            }
            #pragma unroll
            for (int j = 0; j < 2; ++j) {
                const float* xp = xc + (R0 + (ng * 2 + j) * 16 + lc) * 64 + k0;
                float4 v0 = *(const float4*)xp;
                float4 v1 = *(const float4*)(xp + 4);
                bf16x8 h8, l8;
                h8[0] = (__bf16)v0.x; l8[0] = (__bf16)(v0.x - (float)h8[0]);
                h8[1] = (__bf16)v0.y; l8[1] = (__bf16)(v0.y - (float)h8[1]);
                h8[2] = (__bf16)v0.z; l8[2] = (__bf16)(v0.z - (float)h8[2]);
                h8[3] = (__bf16)v0.w; l8[3] = (__bf16)(v0.w - (float)h8[3]);
                h8[4] = (__bf16)v1.x; l8[4] = (__bf16)(v1.x - (float)h8[4]);
                h8[5] = (__bf16)v1.y; l8[5] = (__bf16)(v1.y - (float)h8[5]);
                h8[6] = (__bf16)v1.z; l8[6] = (__bf16)(v1.z - (float)h8[6]);
                h8[7] = (__bf16)v1.w; l8[7] = (__bf16)(v1.w - (float)h8[7]);
                bhi[j] = h8; blo[j] = l8;
            }
            #pragma unroll
            for (int i = 0; i < 4; ++i)
                #pragma unroll
                for (int j = 0; j < 2; ++j) {
                    acc[i][j] = __builtin_amdgcn_mfma_f32_16x16x32_bf16(alo[i], bhi[j], acc[i][j], 0, 0, 0);
                    acc[i][j] = __builtin_amdgcn_mfma_f32_16x16x32_bf16(ahi[i], blo[j], acc[i][j], 0, 0, 0);
                    acc[i][j] = __builtin_amdgcn_mfma_f32_16x16x32_bf16(ahi[i], bhi[j], acc[i][j], 0, 0, 0);
                }
        }
        // epilogue: D[m=h][n=batch]; lane: h0=tile*16+quad*4 (4 consec), batch=lc
        #pragma unroll
        for (int i = 0; i < 4; ++i) {
            int h0 = (hg * 4 + i) * 16 + quad * 4;
            float4 bb = *(const float4*)(b1g + h0);
            #pragma unroll
            for (int j = 0; j < 2; ++j) {
                int r = (ng * 2 + j) * 16 + lc;
                bf16x4 ph, pl;
                float v;
                v = fmaxf(acc[i][j][0] + bb.x, 0.f); ph[0] = (__bf16)v; pl[0] = (__bf16)(v - (float)ph[0]);
                v = fmaxf(acc[i][j][1] + bb.y, 0.f); ph[1] = (__bf16)v; pl[1] = (__bf16)(v - (float)ph[1]);
                v = fmaxf(acc[i][j][2] + bb.z, 0.f); ph[2] = (__bf16)v; pl[2] = (__bf16)(v - (float)ph[2]);
                v = fmaxf(acc[i][j][3] + bb.w, 0.f); ph[3] = (__bf16)v; pl[3] = (__bf16)(v - (float)ph[3]);
                int off = hswz(r, h0);
                *(bf16x4*)(sHhi + off) = ph;
                *(bf16x4*)(sHlo + off) = pl;
            }
        }
    }
    __syncthreads();

    // ---- Phase B: GEMM2  P^T(96x64) = W2T(96x256) @ H^T(256x64) ------------
    // wave: pg = w&1 -> p-tiles pg*3+i; nt = w>>2*... nt = w>>1 -> batch-tile
    {
        const int pg = w & 1, nt = w >> 1;
        const int r = nt * 16 + lc;
        f32x4 acc[3] = {};
        #pragma unroll
        for (int kb = 0; kb < 8; ++kb) {
            const int k0 = kb * 32 + quad * 8;
            const int off = hswz(r, k0);
            bf16x8 hh = *(const bf16x8*)(sHhi + off);
            bf16x8 hl = *(const bf16x8*)(sHlo + off);
            #pragma unroll
            for (int i = 0; i < 3; ++i) {
                int pr = (pg * 3 + i) * 16 + lc;
                bf16x8 whi = *(const bf16x8*)(w2hi + pr * 256 + k0);
                bf16x8 wlo = *(const bf16x8*)(w2lo + pr * 256 + k0);
                acc[i] = __builtin_amdgcn_mfma_f32_16x16x32_bf16(wlo, hh, acc[i], 0, 0, 0);
                acc[i] = __builtin_amdgcn_mfma_f32_16x16x32_bf16(whi, hl, acc[i], 0, 0, 0);
                acc[i] = __builtin_amdgcn_mfma_f32_16x16x32_bf16(whi, hh, acc[i], 0, 0, 0);
            }
        }
        __syncthreads();   // all sH reads done before sP (alias) is written
        float ev = etag[0];
        #pragma unroll
        for (int i = 0; i < 3; ++i) {
            int p0 = (pg * 3 + i) * 16 + quad * 4;
            float4 bb = *(const float4*)(b2g + p0);
            float* dst = sP + r * 97 + p0;
            dst[0] = (acc[i][0] + bb.x) * ev;
            dst[1] = (acc[i][1] + bb.y) * ev;
            dst[2] = (acc[i][2] + bb.z) * ev;
            dst[3] = (acc[i][3] + bb.w) * ev;
        }
    }
    __syncthreads();

    // ---- Phase C: spline knots (widths t<64, heights 64<=t<128) ------------
    // In-place: col j ends holding knot_{j+1}; knot_0 = 0 implicit.
    if (t < 128) {
        int r = t & 63;
        float* row = sP + r * 97 + ((t >> 6) << 5);
        float mx = row[0];
        #pragma unroll
        for (int j = 1; j < 32; ++j) mx = fmaxf(mx, row[j]);
        float S = 0.f;
        #pragma unroll
        for (int j = 0; j < 32; ++j) {
            float e = __expf(row[j] - mx);
            row[j] = e;
            S += e;
        }
        float scale = (1.0f - 32.0f * MIN_SZ) / S;
        float c = 0.f;
        #pragma unroll
        for (int j = 0; j < 32; ++j) {
            c += row[j];
            row[j] = TWO_PI_F * fmaf(scale, c, MIN_SZ * (float)(j + 1));
        }
        row[31] = TWO_PI_F;
    }
    __syncthreads();

    // ---- Phase D: bin search + rational-quadratic + store ------------------
    if (t < 64) {
        const float* row = sP + t * 97;
        float th_in = theta[R0 + t];
        int bin = 0;
        #pragma unroll
        for (int j = 0; j < 32; ++j) bin += (th_in >= row[j]) ? 1 : 0;
        bin = min(bin, 31);

        float cwk1 = row[bin];
        float cwk0 = (bin == 0) ? 0.f : row[bin - 1];
        float chk1 = row[32 + bin];
        float chk0 = (bin == 0) ? 0.f : row[32 + bin - 1];
        float in_w = cwk1 - cwk0;
        float in_h = chk1 - chk0;
        float d_k  = MIN_D_F + softplus_f(row[64 + bin] + DERIV_OFF);
        float d_k1 = MIN_D_F + softplus_f(row[64 + ((bin + 1) & 31)] + DERIV_OFF);

        float s   = in_h / in_w;
        float tt  = (th_in - cwk0) / in_w;
        float tom = tt * (1.f - tt);
        float denom = s + (d_k1 + d_k - 2.f * s) * tom;
        float numer = in_h * (s * tt * tt + d_k * tom);
        float outv  = chk0 + numer / denom;
        float omt   = 1.f - tt;
        float dnum  = s * s * (d_k1 * tt * tt + 2.f * s * tom + d_k * omt * omt);
        float lad   = __logf(dnum) - 2.f * __logf(denom);

        out[R0 + t]              = outv;
        out[(long)Btot + R0 + t] = lad;
    }
}

extern "C" void kernel_launch(void* const* d_in, const int* in_sizes, int n_in,
                              void* d_out, int out_size, void* d_ws, size_t ws_size,
                              hipStream_t stream) {
    const float* theta = (const float*)d_in[0];
    const float* xcond = (const float*)d_in[1];
    const float* W1    = (const float*)d_in[2];
    const float* b1    = (const float*)d_in[3];
    const float* W2    = (const float*)d_in[4];
    const float* b2    = (const float*)d_in[5];
    const float* eta   = (const float*)d_in[6];
    int Btot = in_sizes[0];                    // 1048576 (d = 1)

    __bf16* w1hi = (__bf16*)d_ws;              // 256*64
    __bf16* w1lo = w1hi + 64 * 256;
    __bf16* w2hi = w1lo + 64 * 256;            // 96*256
    __bf16* w2lo = w2hi + 96 * 256;            // total 160 KiB of ws

    flow_prep<<<160, 256, 0, stream>>>(W1, W2, w1hi, w1lo, w2hi, w2lo);
    flow_main<<<Btot / 64, 512, 0, stream>>>(theta, xcond, b1, b2, eta,
                                             w1hi, w1lo, w2hi, w2lo,
                                             (float*)d_out, Btot);
}

// Round 4
// 776.220 us; speedup vs baseline: 1.7431x; 1.7431x over previous
//
#include <hip/hip_runtime.h>

// ---------------------------------------------------------------------------
// Cylindrical flow: h = relu(x@W1+b1); params = (h@W2+b2)*eta; circular RQ
// spline. B=1048576, N=64, H=256, nb=32.
// R4 = R3's coalesced fragment-packed structure + split-fp16 3-pass MFMA.
//   - fp16 single-pass (R3) -> logabsdet absmax 0.54 (log-deriv amplifies
//     ~1e-3 logit noise by ~1/min_bin_width). Split hi/lo fp16, 3 MFMA terms
//     (hi*hi + hi*lo + lo*hi) -> eff rel err ~2^-22 ~ fp32 (R2-proven level).
//   - Weights packed in MFMA-fragment order (1 KB contiguous per wave-load;
//     R2's 1140 us came from 64-transaction uncoalesced weight loads).
//   - M=64 rows/block, 512 thr; H hi/lo fp16 XOR-swizzled, 64 KB LDS ->
//     2 blocks/CU. MFMA-bound floor ~124 us (3 x 85.9 GF @ 2075 TF).
// ---------------------------------------------------------------------------

typedef _Float16 f16x8 __attribute__((ext_vector_type(8)));
typedef _Float16 f16x4 __attribute__((ext_vector_type(4)));
typedef float    f32x4 __attribute__((ext_vector_type(4)));

#define TWO_PI_F  6.28318530717958647692f
#define MIN_SZ    1e-3f
#define MIN_D_F   1e-3f
#define DERIV_OFF 0.54132485461291810f   /* ln(e-1) */

__device__ __forceinline__ float softplus_f(float x) {
    return fmaxf(x, 0.f) + log1pf(__expf(-fabsf(x)));
}

// Swizzled LDS offset (elements) for H[m][h]: row stride 256 f16, 8-elem
// chunks XORed by m&7 -> <=2-way banks for b64 writes and b128 reads.
__device__ __forceinline__ int hswz(int r, int h) {
    return r * 256 + ((((h >> 3) ^ (r & 7)) << 3) | (h & 7));
}

// Pack weights into MFMA A-fragment order (hi + lo fp16):
// frag(tile,kb): lane l holds row = tile*16+(l&15), k = kb*32+(l>>4)*8+j.
__global__ void flow_prep(const float* __restrict__ W1, const float* __restrict__ W2,
                          _Float16* __restrict__ w1h, _Float16* __restrict__ w1l,
                          _Float16* __restrict__ w2h, _Float16* __restrict__ w2l) {
    int i = blockIdx.x * 256 + threadIdx.x;
    if (i < 16384) {                       // w1: [16 ht][2 kb][64 l][8 j]
        int j = i & 7, l = (i >> 3) & 63, kb = (i >> 9) & 1, ht = i >> 10;
        int h = ht * 16 + (l & 15);
        int k = kb * 32 + (l >> 4) * 8 + j;
        float v = W1[k * 256 + h];         // W1 (64,256) row-major
        _Float16 hv = (_Float16)v;
        w1h[i] = hv;
        w1l[i] = (_Float16)(v - (float)hv);
    }
    int i2 = i - 16384;
    if (i2 >= 0 && i2 < 24576) {           // w2: [6 pt][8 kb][64 l][8 j]
        int j = i2 & 7, l = (i2 >> 3) & 63, kb = (i2 >> 9) & 7, pt = i2 >> 12;
        int p = pt * 16 + (l & 15);
        int k = kb * 32 + (l >> 4) * 8 + j;
        float v = W2[k * 96 + p];          // W2 (256,96) row-major
        _Float16 hv = (_Float16)v;
        w2h[i2] = hv;
        w2l[i2] = (_Float16)(v - (float)hv);
    }
}

__global__ __launch_bounds__(512, 4) void flow_main(
    const float* __restrict__ theta, const float* __restrict__ xc,
    const float* __restrict__ b1g, const float* __restrict__ b2g,
    const float* __restrict__ etag,
    const _Float16* __restrict__ w1h, const _Float16* __restrict__ w1l,
    const _Float16* __restrict__ w2h, const _Float16* __restrict__ w2l,
    float* __restrict__ out, int Btot)
{
    __shared__ __align__(16) char smem[65536];
    _Float16* sHhi = (_Float16*)smem;             // [64][256] swizzled, 32 KiB
    _Float16* sHlo = (_Float16*)(smem + 32768);   // [64][256] swizzled, 32 KiB
    float*    sP   = (float*)smem;                // [64][97], aliases sHhi

    const int t    = threadIdx.x;
    const int w    = t >> 6;
    const int l    = t & 63;
    const int quad = l >> 4;
    const int lc   = l & 15;
    const long R0  = (long)blockIdx.x * 64;

    // ---- GEMM1: H^T(256h x 64m) = W1T(256x64) @ X^T(64x64) -----------------
    // wave: hg = w>>1 (4 h-tiles), mg = w&1 (2 m-tiles)
    {
        const int hg = w >> 1, mg = w & 1;
        const f16x8* w1vh = (const f16x8*)w1h;
        const f16x8* w1vl = (const f16x8*)w1l;
        f32x4 acc[4][2] = {};
        #pragma unroll
        for (int kb = 0; kb < 2; ++kb) {
            f16x8 ah[4], al[4], bh[2], bl[2];
            #pragma unroll
            for (int i = 0; i < 4; ++i) {
                int fi = ((hg * 4 + i) * 2 + kb) * 64 + l;   // 1 KB coalesced
                ah[i] = w1vh[fi];
                al[i] = w1vl[fi];
            }
            #pragma unroll
            for (int j = 0; j < 2; ++j) {
                const float* xp = xc + (R0 + (mg * 2 + j) * 16 + lc) * 64
                                     + kb * 32 + quad * 8;
                float4 v0 = *(const float4*)xp;
                float4 v1 = *(const float4*)(xp + 4);
                f16x8 hh, ll;
                hh[0] = (_Float16)v0.x; ll[0] = (_Float16)(v0.x - (float)hh[0]);
                hh[1] = (_Float16)v0.y; ll[1] = (_Float16)(v0.y - (float)hh[1]);
                hh[2] = (_Float16)v0.z; ll[2] = (_Float16)(v0.z - (float)hh[2]);
                hh[3] = (_Float16)v0.w; ll[3] = (_Float16)(v0.w - (float)hh[3]);
                hh[4] = (_Float16)v1.x; ll[4] = (_Float16)(v1.x - (float)hh[4]);
                hh[5] = (_Float16)v1.y; ll[5] = (_Float16)(v1.y - (float)hh[5]);
                hh[6] = (_Float16)v1.z; ll[6] = (_Float16)(v1.z - (float)hh[6]);
                hh[7] = (_Float16)v1.w; ll[7] = (_Float16)(v1.w - (float)hh[7]);
                bh[j] = hh; bl[j] = ll;
            }
            #pragma unroll
            for (int i = 0; i < 4; ++i)
                #pragma unroll
                for (int j = 0; j < 2; ++j) {
                    acc[i][j] = __builtin_amdgcn_mfma_f32_16x16x32_f16(al[i], bh[j], acc[i][j], 0, 0, 0);
                    acc[i][j] = __builtin_amdgcn_mfma_f32_16x16x32_f16(ah[i], bl[j], acc[i][j], 0, 0, 0);
                    acc[i][j] = __builtin_amdgcn_mfma_f32_16x16x32_f16(ah[i], bh[j], acc[i][j], 0, 0, 0);
                }
        }
        // epilogue: D[h][m]; lane holds h0..h0+3 at col m -> b64 LDS writes
        #pragma unroll
        for (int i = 0; i < 4; ++i) {
            int h0 = (hg * 4 + i) * 16 + quad * 4;
            float4 bb = *(const float4*)(b1g + h0);
            #pragma unroll
            for (int j = 0; j < 2; ++j) {
                int m = (mg * 2 + j) * 16 + lc;
                f16x4 ph, pl;
                float v;
                v = fmaxf(acc[i][j][0] + bb.x, 0.f); ph[0] = (_Float16)v; pl[0] = (_Float16)(v - (float)ph[0]);
                v = fmaxf(acc[i][j][1] + bb.y, 0.f); ph[1] = (_Float16)v; pl[1] = (_Float16)(v - (float)ph[1]);
                v = fmaxf(acc[i][j][2] + bb.z, 0.f); ph[2] = (_Float16)v; pl[2] = (_Float16)(v - (float)ph[2]);
                v = fmaxf(acc[i][j][3] + bb.w, 0.f); ph[3] = (_Float16)v; pl[3] = (_Float16)(v - (float)ph[3]);
                int off = hswz(m, h0);
                *(f16x4*)(sHhi + off) = ph;
                *(f16x4*)(sHlo + off) = pl;
            }
        }
    }
    __syncthreads();

    // ---- GEMM2: P^T(96p x 64m) = W2T(96x256) @ H^T(256x64) -----------------
    // wave: pg = w&1 (3 p-tiles), mt = w>>1 (1 m-tile)
    {
        const int pg = w & 1, mt = w >> 1;
        const int r = mt * 16 + lc;
        const f16x8* w2vh = (const f16x8*)w2h;
        const f16x8* w2vl = (const f16x8*)w2l;
        f32x4 acc[3] = {};
        #pragma unroll
        for (int kb = 0; kb < 8; ++kb) {
            const int k0 = kb * 32 + quad * 8;
            const int off = hswz(r, k0);
            f16x8 bhv = *(const f16x8*)(sHhi + off);
            f16x8 blv = *(const f16x8*)(sHlo + off);
            #pragma unroll
            for (int i = 0; i < 3; ++i) {
                int fi = ((pg * 3 + i) * 8 + kb) * 64 + l;     // 1 KB coalesced
                f16x8 av = w2vh[fi];
                f16x8 alv = w2vl[fi];
                acc[i] = __builtin_amdgcn_mfma_f32_16x16x32_f16(alv, bhv, acc[i], 0, 0, 0);
                acc[i] = __builtin_amdgcn_mfma_f32_16x16x32_f16(av, blv, acc[i], 0, 0, 0);
                acc[i] = __builtin_amdgcn_mfma_f32_16x16x32_f16(av, bhv, acc[i], 0, 0, 0);
            }
        }
        __syncthreads();   // all sH reads done before sP (alias) is written
        float ev = etag[0];
        #pragma unroll
        for (int i = 0; i < 3; ++i) {
            int p0 = (pg * 3 + i) * 16 + quad * 4;
            float4 bb = *(const float4*)(b2g + p0);
            float* dst = sP + r * 97 + p0;   // stride 97 = 1 mod 32: conflict-free
            dst[0] = (acc[i][0] + bb.x) * ev;
            dst[1] = (acc[i][1] + bb.y) * ev;
            dst[2] = (acc[i][2] + bb.z) * ev;
            dst[3] = (acc[i][3] + bb.w) * ev;
        }
    }
    __syncthreads();

    // ---- Spline knots: widths (t<64) / heights (64<=t<128) -----------------
    // In-place: col j ends holding knot_{j+1}; knot_0 = 0 implicit.
    if (t < 128) {
        int r = t & 63;
        float* row = sP + r * 97 + ((t >> 6) << 5);
        float mx = row[0];
        #pragma unroll
        for (int j = 1; j < 32; ++j) mx = fmaxf(mx, row[j]);
        float S = 0.f;
        #pragma unroll
        for (int j = 0; j < 32; ++j) {
            float e = __expf(row[j] - mx);
            row[j] = e;
            S += e;
        }
        float scale = (1.0f - 32.0f * MIN_SZ) / S;
        float c = 0.f;
        #pragma unroll
        for (int j = 0; j < 32; ++j) {
            c += row[j];
            row[j] = TWO_PI_F * fmaf(scale, c, MIN_SZ * (float)(j + 1));
        }
        row[31] = TWO_PI_F;
    }
    __syncthreads();

    // ---- Bin search + rational-quadratic + store ---------------------------
    if (t < 64) {
        const float* row = sP + t * 97;
        float th_in = theta[R0 + t];
        int bin = 0;
        #pragma unroll
        for (int j = 0; j < 32; ++j) bin += (th_in >= row[j]) ? 1 : 0;
        bin = min(bin, 31);

        float cwk1 = row[bin];
        float cwk0 = (bin == 0) ? 0.f : row[bin - 1];
        float chk1 = row[32 + bin];
        float chk0 = (bin == 0) ? 0.f : row[32 + bin - 1];
        float in_w = cwk1 - cwk0;
        float in_h = chk1 - chk0;
        float d_k  = MIN_D_F + softplus_f(row[64 + bin] + DERIV_OFF);
        float d_k1 = MIN_D_F + softplus_f(row[64 + ((bin + 1) & 31)] + DERIV_OFF);

        float s   = in_h / in_w;
        float tt  = (th_in - cwk0) / in_w;
        float tom = tt * (1.f - tt);
        float denom = s + (d_k1 + d_k - 2.f * s) * tom;
        float numer = in_h * (s * tt * tt + d_k * tom);
        float outv  = chk0 + numer / denom;
        float omt   = 1.f - tt;
        float dnum  = s * s * (d_k1 * tt * tt + 2.f * s * tom + d_k * omt * omt);
        float lad   = __logf(dnum) - 2.f * __logf(denom);

        out[R0 + t]              = outv;
        out[(long)Btot + R0 + t] = lad;
    }
}

extern "C" void kernel_launch(void* const* d_in, const int* in_sizes, int n_in,
                              void* d_out, int out_size, void* d_ws, size_t ws_size,
                              hipStream_t stream) {
    const float* theta = (const float*)d_in[0];
    const float* xcond = (const float*)d_in[1];
    const float* W1    = (const float*)d_in[2];
    const float* b1    = (const float*)d_in[3];
    const float* W2    = (const float*)d_in[4];
    const float* b2    = (const float*)d_in[5];
    const float* eta   = (const float*)d_in[6];
    int Btot = in_sizes[0];                    // 1048576 (d = 1)

    _Float16* w1h = (_Float16*)d_ws;           // 16384 f16
    _Float16* w1l = w1h + 16384;
    _Float16* w2h = w1l + 16384;               // 24576 f16
    _Float16* w2l = w2h + 24576;               // total 160 KiB of ws

    flow_prep<<<160, 256, 0, stream>>>(W1, W2, w1h, w1l, w2h, w2l);
    flow_main<<<Btot / 64, 512, 0, stream>>>(theta, xcond, b1, b2, eta,
                                             w1h, w1l, w2h, w2l,
                                             (float*)d_out, Btot);
}

// Round 5
// 710.093 us; speedup vs baseline: 1.9054x; 1.0931x over previous
//
#include <hip/hip_runtime.h>

// ---------------------------------------------------------------------------
// Cylindrical flow, R5: barrier-free wave-fused pipeline.
//   - Split-fp16 3-pass MFMA (R4-proven precision, absmax 0.031).
//   - K-permutation trick: GEMM2's K-dim is permuted so GEMM1's MFMA C-layout
//     output IS GEMM2's B-fragment (W2 packed with matching permutation at
//     prep). H stays in registers: no LDS round-trip, no cross-lane moves.
//   - One wave owns 64 rows end-to-end (GEMM1+GEMM2+spline); no __syncthreads
//     in the main path (one at block start for bias staging only).
//   - Spline in per-wave LDS scratch (32 rows x 2 rounds), 64/64 lanes active
//     in knot phase. R4 stalled 4 barriers/64 rows -> 47% combined util.
// ---------------------------------------------------------------------------

typedef _Float16 f16x8 __attribute__((ext_vector_type(8)));
typedef float    f32x4 __attribute__((ext_vector_type(4)));

#define TWO_PI_F  6.28318530717958647692f
#define MIN_SZ    1e-3f
#define MIN_D_F   1e-3f
#define DERIV_OFF 0.54132485461291810f   /* ln(e-1) */

__device__ __forceinline__ float softplus_f(float x) {
    return fmaxf(x, 0.f) + log1pf(__expf(-fabsf(x)));
}

// ---------------------------------------------------------------------------
// Prep: pack W1 (std A-fragment order) and W2 (K-permuted A-fragment order),
// each as hi/lo fp16 split.
// W1 frag (ht,kx): lane l, j: A[h = ht*16+(l&15)][k = kx*32+(l>>4)*8+j]
// W2 frag (pt,kb): lane l, j: A[p = pt*16+(l&15)][h = (2kb+(j>>2))*16+(l>>4)*4+(j&3)]
// ---------------------------------------------------------------------------
__global__ void flow_prep(const float* __restrict__ W1, const float* __restrict__ W2,
                          _Float16* __restrict__ w1h, _Float16* __restrict__ w1l,
                          _Float16* __restrict__ w2h, _Float16* __restrict__ w2l) {
    int i = blockIdx.x * 256 + threadIdx.x;
    if (i < 16384) {                       // w1: [16 ht][2 kx][64 l][8 j]
        int j = i & 7, l = (i >> 3) & 63, kx = (i >> 9) & 1, ht = i >> 10;
        int h = ht * 16 + (l & 15);
        int k = kx * 32 + (l >> 4) * 8 + j;
        float v = W1[k * 256 + h];         // W1 (64,256) row-major
        _Float16 hv = (_Float16)v;
        w1h[i] = hv;
        w1l[i] = (_Float16)(v - (float)hv);
    }
    int i2 = i - 16384;
    if (i2 >= 0 && i2 < 24576) {           // w2: [6 pt][8 kb][64 l][8 j], K-permuted
        int j = i2 & 7, l = (i2 >> 3) & 63, kb = (i2 >> 9) & 7, pt = i2 >> 12;
        int p = pt * 16 + (l & 15);
        int h = (2 * kb + (j >> 2)) * 16 + ((l >> 4) << 2) + (j & 3);
        float v = W2[h * 96 + p];          // W2 (256,96) row-major
        _Float16 hv = (_Float16)v;
        w2h[i2] = hv;
        w2l[i2] = (_Float16)(v - (float)hv);
    }
}

__global__ __launch_bounds__(256, 2) void flow_main(
    const float* __restrict__ theta, const float* __restrict__ xc,
    const float* __restrict__ b1g, const float* __restrict__ b2g,
    const float* __restrict__ etag,
    const _Float16* __restrict__ w1h, const _Float16* __restrict__ w1l,
    const _Float16* __restrict__ w2h, const _Float16* __restrict__ w2l,
    float* __restrict__ out, int Btot)
{
    __shared__ __align__(16) float sP[4 * 32 * 97];   // per-wave 32x97 scratch
    __shared__ float sB1[256];
    __shared__ float sB2[96];

    const int t   = threadIdx.x;
    const int wid = t >> 6;
    const int l   = t & 63;
    const int q   = l >> 4;
    const int lc  = l & 15;
    const long R0w = ((long)blockIdx.x * 4 + wid) * 64;

    if (t < 256) sB1[t] = b1g[t];
    if (t < 96)  sB2[t] = b2g[t];
    __syncthreads();                       // only barrier in the kernel
    const float ev = etag[0];

    const f16x8* w1vh = (const f16x8*)w1h;
    const f16x8* w1vl = (const f16x8*)w1l;
    const f16x8* w2vh = (const f16x8*)w2h;
    const f16x8* w2vl = (const f16x8*)w2l;

    // ---- load x fragments for this wave's 64 rows (persistent) -------------
    f16x8 xh[4][2], xl[4][2];
    #pragma unroll
    for (int mt = 0; mt < 4; ++mt)
        #pragma unroll
        for (int kx = 0; kx < 2; ++kx) {
            const float* xp = xc + (R0w + mt * 16 + lc) * 64 + kx * 32 + q * 8;
            float4 v0 = *(const float4*)xp;
            float4 v1 = *(const float4*)(xp + 4);
            float a[8] = {v0.x, v0.y, v0.z, v0.w, v1.x, v1.y, v1.z, v1.w};
            f16x8 hi, lo;
            #pragma unroll
            for (int e = 0; e < 8; ++e) {
                _Float16 hv = (_Float16)a[e];
                hi[e] = hv;
                lo[e] = (_Float16)(a[e] - (float)hv);
            }
            xh[mt][kx] = hi;
            xl[mt][kx] = lo;
        }

    // ---- fused K-loop: per kb, GEMM1 (2 h-tiles) -> relu/split -> GEMM2 ----
    f32x4 acc2[6][4] = {};
    #pragma unroll 2
    for (int kb = 0; kb < 8; ++kb) {
        f32x4 a1[2][4] = {};
        #pragma unroll
        for (int i = 0; i < 2; ++i) {
            const int ht = 2 * kb + i;
            #pragma unroll
            for (int kx = 0; kx < 2; ++kx) {
                f16x8 wh = w1vh[(ht * 2 + kx) * 64 + l];   // 1 KB coalesced
                f16x8 wl = w1vl[(ht * 2 + kx) * 64 + l];
                #pragma unroll
                for (int mt = 0; mt < 4; ++mt) {
                    a1[i][mt] = __builtin_amdgcn_mfma_f32_16x16x32_f16(wl, xh[mt][kx], a1[i][mt], 0, 0, 0);
                    a1[i][mt] = __builtin_amdgcn_mfma_f32_16x16x32_f16(wh, xl[mt][kx], a1[i][mt], 0, 0, 0);
                    a1[i][mt] = __builtin_amdgcn_mfma_f32_16x16x32_f16(wh, xh[mt][kx], a1[i][mt], 0, 0, 0);
                }
            }
        }
        // epilogue: bias+relu+split; GEMM1 C-layout IS GEMM2 B-frag (K-perm)
        f16x8 bh[4], bl[4];
        float4 bb0 = *(const float4*)(sB1 + (2 * kb + 0) * 16 + q * 4);
        float4 bb1 = *(const float4*)(sB1 + (2 * kb + 1) * 16 + q * 4);
        #pragma unroll
        for (int mt = 0; mt < 4; ++mt) {
            float vv[8] = {
                fmaxf(a1[0][mt][0] + bb0.x, 0.f), fmaxf(a1[0][mt][1] + bb0.y, 0.f),
                fmaxf(a1[0][mt][2] + bb0.z, 0.f), fmaxf(a1[0][mt][3] + bb0.w, 0.f),
                fmaxf(a1[1][mt][0] + bb1.x, 0.f), fmaxf(a1[1][mt][1] + bb1.y, 0.f),
                fmaxf(a1[1][mt][2] + bb1.z, 0.f), fmaxf(a1[1][mt][3] + bb1.w, 0.f)};
            f16x8 hi, lo;
            #pragma unroll
            for (int e = 0; e < 8; ++e) {
                _Float16 hv = (_Float16)vv[e];
                hi[e] = hv;
                lo[e] = (_Float16)(vv[e] - (float)hv);
            }
            bh[mt] = hi;
            bl[mt] = lo;
        }
        #pragma unroll
        for (int pt = 0; pt < 6; ++pt) {
            f16x8 wh = w2vh[(pt * 8 + kb) * 64 + l];       // 1 KB coalesced
            f16x8 wl = w2vl[(pt * 8 + kb) * 64 + l];
            #pragma unroll
            for (int mt = 0; mt < 4; ++mt) {
                acc2[pt][mt] = __builtin_amdgcn_mfma_f32_16x16x32_f16(wl, bh[mt], acc2[pt][mt], 0, 0, 0);
                acc2[pt][mt] = __builtin_amdgcn_mfma_f32_16x16x32_f16(wh, bl[mt], acc2[pt][mt], 0, 0, 0);
                acc2[pt][mt] = __builtin_amdgcn_mfma_f32_16x16x32_f16(wh, bh[mt], acc2[pt][mt], 0, 0, 0);
            }
        }
    }

    // ---- spline: 2 rounds of 32 rows, wave-private LDS, no barriers --------
    float* sPw = sP + wid * (32 * 97);
    #pragma unroll 1
    for (int rd = 0; rd < 2; ++rd) {
        // write P[r][p] = (acc2 + b2)*eta ; r = mtl*16+lc, p = pt*16+q*4
        #pragma unroll
        for (int pt = 0; pt < 6; ++pt) {
            float4 bb = *(const float4*)(sB2 + pt * 16 + q * 4);
            #pragma unroll
            for (int mtl = 0; mtl < 2; ++mtl) {
                f32x4 v = acc2[pt][rd * 2 + mtl];
                float* dst = sPw + (mtl * 16 + lc) * 97 + pt * 16 + q * 4;
                dst[0] = (v[0] + bb.x) * ev;
                dst[1] = (v[1] + bb.y) * ev;
                dst[2] = (v[2] + bb.z) * ev;
                dst[3] = (v[3] + bb.w) * ev;
            }
        }
        // knots: 64 lanes = 32 rows x {widths, heights}; in-place, col j ends
        // holding knot_{j+1} (knot_0 = 0 implicit)
        {
            int row = l & 31;
            float* rowp = sPw + row * 97 + ((l >> 5) << 5);
            float mx = rowp[0];
            #pragma unroll
            for (int j = 1; j < 32; ++j) mx = fmaxf(mx, rowp[j]);
            float S = 0.f;
            #pragma unroll
            for (int j = 0; j < 32; ++j) {
                float e = __expf(rowp[j] - mx);
                rowp[j] = e;
                S += e;
            }
            float scale = (1.0f - 32.0f * MIN_SZ) / S;
            float c = 0.f;
            #pragma unroll
            for (int j = 0; j < 32; ++j) {
                c += rowp[j];
                rowp[j] = TWO_PI_F * fmaf(scale, c, MIN_SZ * (float)(j + 1));
            }
            rowp[31] = TWO_PI_F;
        }
        // eval + store: lanes 0..31
        if (l < 32) {
            const float* row = sPw + l * 97;
            long gr = R0w + rd * 32 + l;
            float th_in = theta[gr];
            int bin = 0;
            #pragma unroll
            for (int j = 0; j < 32; ++j) bin += (th_in >= row[j]) ? 1 : 0;
            bin = min(bin, 31);

            float cwk1 = row[bin];
            float cwk0 = (bin == 0) ? 0.f : row[bin - 1];
            float chk1 = row[32 + bin];
            float chk0 = (bin == 0) ? 0.f : row[32 + bin - 1];
            float in_w = cwk1 - cwk0;
            float in_h = chk1 - chk0;
            float d_k  = MIN_D_F + softplus_f(row[64 + bin] + DERIV_OFF);
            float d_k1 = MIN_D_F + softplus_f(row[64 + ((bin + 1) & 31)] + DERIV_OFF);

            float s   = in_h / in_w;
            float tt  = (th_in - cwk0) / in_w;
            float tom = tt * (1.f - tt);
            float denom = s + (d_k1 + d_k - 2.f * s) * tom;
            float numer = in_h * (s * tt * tt + d_k * tom);
            float outv  = chk0 + numer / denom;
            float omt   = 1.f - tt;
            float dnum  = s * s * (d_k1 * tt * tt + 2.f * s * tom + d_k * omt * omt);
            float lad   = __logf(dnum) - 2.f * __logf(denom);

            out[gr]               = outv;
            out[(long)Btot + gr]  = lad;
        }
    }
}

extern "C" void kernel_launch(void* const* d_in, const int* in_sizes, int n_in,
                              void* d_out, int out_size, void* d_ws, size_t ws_size,
                              hipStream_t stream) {
    const float* theta = (const float*)d_in[0];
    const float* xcond = (const float*)d_in[1];
    const float* W1    = (const float*)d_in[2];
    const float* b1    = (const float*)d_in[3];
    const float* W2    = (const float*)d_in[4];
    const float* b2    = (const float*)d_in[5];
    const float* eta   = (const float*)d_in[6];
    int Btot = in_sizes[0];                    // 1048576 (d = 1)

    _Float16* w1h = (_Float16*)d_ws;           // 16384 f16
    _Float16* w1l = w1h + 16384;
    _Float16* w2h = w1l + 16384;               // 24576 f16
    _Float16* w2l = w2h + 24576;               // total 160 KiB of ws

    flow_prep<<<160, 256, 0, stream>>>(W1, W2, w1h, w1l, w2h, w2l);
    // 64 rows per wave, 4 waves per block -> 256 rows/block
    flow_main<<<Btot / 256, 256, 0, stream>>>(theta, xcond, b1, b2, eta,
                                              w1h, w1l, w2h, w2l,
                                              (float*)d_out, Btot);
}